// Round 8
// baseline (2359.609 us; speedup 1.0000x reference)
//
#include <hip/hip_runtime.h>

// GNN27: two-branch diffusion GCN (N=8192, F_IN=11, F1=16, F2=32) + multi-head
// tanh-attention pooling. All fp32. Memory-bound on the two 268MB adjacencies,
// each streamed twice -> 1.07GB unique traffic.
//
// R1-R6: A read as <=1KB-granular parallel row streams -> 0.9-1.9 TB/s
// regardless of structure (direct / global_load_lds DMA / flat-TLP).
// R7: 4-8KB sequential runs per row -> raw 3.07 TB/s CONFIRMED, but 128-reg
// cap spilled (1.5GB scratch) + staging bank conflicts ate the win.
// R8: k-dot layout. P window in LDS in natural PT layout plds[f][W]:
// staging = straight coalesced copy (linear LDS writes, 0 conflicts); compute
// reads lane-contiguous b128 (0 conflicts); acc[r][f] += dot(a4, pv4) keeps
// P out of registers entirely (~110 VGPR, no spill). Block owns one K-window
// (split-K), stages once, barrier-free per-wave row pipeline, 2-pair prefetch.
// Branches sequential to keep partials inside the proven 23MB ws footprint.

constexpr int N = 8192;

// ---------------- kernel 1: P1T = (x @ W1)^T   ([16][N]) ----------------
__global__ void k_dense_in(const float* __restrict__ x0, const float* __restrict__ x1,
                           const float* __restrict__ W0, const float* __restrict__ W1,
                           float* __restrict__ o0, float* __restrict__ o1) {
    const int branch = blockIdx.y;
    const float* __restrict__ x = branch ? x1 : x0;
    const float* __restrict__ W = branch ? W1 : W0;
    float* __restrict__ o = branch ? o1 : o0;
    __shared__ float sW[11 * 16];
    if (threadIdx.x < 176) sW[threadIdx.x] = W[threadIdx.x];
    __syncthreads();
    const int n = blockIdx.x * blockDim.x + threadIdx.x;  // grid.x*256 == N exactly
    float xr[11];
#pragma unroll
    for (int j = 0; j < 11; ++j) xr[j] = x[n * 11 + j];
    float acc[16];
#pragma unroll
    for (int f = 0; f < 16; ++f) acc[f] = 0.f;
#pragma unroll
    for (int j = 0; j < 11; ++j)
#pragma unroll
        for (int f = 0; f < 16; ++f) acc[f] += xr[j] * sW[j * 16 + f];
#pragma unroll
    for (int f = 0; f < 16; ++f) o[f * N + n] = acc[f];  // transposed, coalesced
}

// ---------------- kernel 3: P2T = (H1 @ W2)^T   ([32][N]) ----------------
__global__ void k_dense_mid(const float* __restrict__ h0, const float* __restrict__ h1,
                            const float* __restrict__ W0, const float* __restrict__ W1,
                            float* __restrict__ o0, float* __restrict__ o1) {
    const int branch = blockIdx.y;
    const float* __restrict__ h = branch ? h1 : h0;
    const float* __restrict__ W = branch ? W1 : W0;
    float* __restrict__ o = branch ? o1 : o0;
    __shared__ float sW[16 * 32];
    for (int i = threadIdx.x; i < 512; i += blockDim.x) sW[i] = W[i];
    __syncthreads();
    const int n = blockIdx.x * blockDim.x + threadIdx.x;
    float hr[16];
#pragma unroll
    for (int q = 0; q < 4; ++q)
        *reinterpret_cast<float4*>(&hr[q * 4]) =
            *reinterpret_cast<const float4*>(&h[n * 16 + q * 4]);
    float acc[32];
#pragma unroll
    for (int f = 0; f < 32; ++f) acc[f] = 0.f;
#pragma unroll
    for (int j = 0; j < 16; ++j)
#pragma unroll
        for (int f = 0; f < 32; ++f) acc[f] += hr[j] * sW[j * 32 + f];
#pragma unroll
    for (int f = 0; f < 32; ++f) o[f * N + n] = acc[f];  // transposed, coalesced
}

// ---- kernels 2 & 4: partial = A @ P over one K-window, k-dot + seq bursts ---
// Block = 512 thr = 8 waves, single branch. Window W floats (F16:1024 F32:512,
// LDS = F*W*4 = 64KB). Stage once (coalesced, linear -> conflict-free), then
// each wave streams its 8 rows: per row the window is C=W/256 back-to-back
// 1KB wave bursts (4KB|2KB sequential). Rows processed in pairs; per (c,f)
// one lane-contiguous b128 P read serves 8 FMAs (2 rows x 4 k). 2-pair-deep
// prefetch; compiler's counted vmcnt leaves the next pair flying. Split-K
// partials -> k_reduce (bias+relu).
template <int F, int W>
__global__ __launch_bounds__(512, 2) void k_spmm(
    const float* __restrict__ A, const float* __restrict__ PT,
    float* __restrict__ pb) {
    constexpr int NS = N / W;    // K-slices: 8 | 16
    constexpr int C = W / 256;   // 1KB bursts per row window: 4 | 2
    constexpr int RPB = 64;      // rows per block = 8 waves * 8
    constexpr int PAIRS = 4;     // row pairs per wave
    constexpr int NV = 2 * F;    // reduce width: 32 | 64

    __shared__ float plds[F * W];  // 64 KB

    const int tid = threadIdx.x;
    const int lane = tid & 63;
    const int wave = tid >> 6;
    const int rb = blockIdx.x / NS, sl = blockIdx.x % NS;
    const int K0 = sl * W;
    const int wrow0 = rb * RPB + wave * 8;

    // stage P window: consecutive tid -> consecutive k (coalesced global,
    // linear LDS) as float4
    constexpr int NF4 = F * W / 4;  // 4096
#pragma unroll
    for (int i = tid; i < NF4; i += 512) {
        const int fl = i / (W / 4);
        const int k4 = i % (W / 4);
        *reinterpret_cast<float4*>(&plds[fl * W + 4 * k4]) =
            *reinterpret_cast<const float4*>(PT + (size_t)fl * N + K0 + 4 * k4);
    }
    __syncthreads();

    const float* __restrict__ Ab = A + (size_t)wrow0 * N + K0 + 4 * lane;

    float4 aB[2][C], bB[2][C];
    float acc[2][F];
#pragma unroll
    for (int r = 0; r < 2; ++r)
#pragma unroll
        for (int f = 0; f < F; ++f) acc[r][f] = 0.f;

    auto loadPair = [&](float4(&buf)[2][C], int p) {
#pragma unroll
        for (int r = 0; r < 2; ++r)
#pragma unroll
            for (int c = 0; c < C; ++c)
                buf[r][c] = *reinterpret_cast<const float4*>(
                    Ab + (size_t)(2 * p + r) * N + c * 256);
    };

    auto compPair = [&](float4(&buf)[2][C]) {
#pragma unroll
        for (int c = 0; c < C; ++c)
#pragma unroll
            for (int f = 0; f < F; ++f) {
                const float4 pv = *reinterpret_cast<const float4*>(
                    &plds[f * W + c * 256 + 4 * lane]);
#pragma unroll
                for (int r = 0; r < 2; ++r) {
                    acc[r][f] += buf[r][c].x * pv.x;
                    acc[r][f] += buf[r][c].y * pv.y;
                    acc[r][f] += buf[r][c].z * pv.z;
                    acc[r][f] += buf[r][c].w * pv.w;
                }
            }
    };

    auto redstore = [&](int p) {
        float v[NV];
#pragma unroll
        for (int i = 0; i < NV; ++i) v[i] = acc[i / F][i % F];
#pragma unroll
        for (int s = 0; (NV >> s) > 1; ++s) {
            const int bit = (lane >> s) & 1;
#pragma unroll
            for (int i = 0; i < (NV >> s); i += 2) {
                const float t0 = __shfl_xor(v[i], 1 << s);
                const float t1 = __shfl_xor(v[i + 1], 1 << s);
                v[i >> 1] = bit ? (v[i + 1] + t1) : (v[i] + t0);
            }
        }
        float r = v[0];
        if constexpr (NV == 32) {  // F=16: halves duplicate; merge + lanes<32 store
            r += __shfl_xor(r, 32);
            if (lane < 32)
                pb[((size_t)sl * N + wrow0 + 2 * p + ((lane >> 4) & 1)) * F + (lane & 15)] = r;
        } else {  // F=32: lane l -> (row=l>>5, f=l&31)
            pb[((size_t)sl * N + wrow0 + 2 * p + (lane >> 5)) * F + (lane & 31)] = r;
        }
#pragma unroll
        for (int rr = 0; rr < 2; ++rr)
#pragma unroll
            for (int f = 0; f < F; ++f) acc[rr][f] = 0.f;
    };

    loadPair(aB, 0);
    loadPair(bB, 1);
#pragma unroll
    for (int p = 0; p < PAIRS; p += 2) {
        compPair(aB);  // waits aB only; bB stays in flight
        redstore(p);
        if (p + 2 < PAIRS) loadPair(aB, p + 2);
        compPair(bB);
        redstore(p + 1);
        if (p + 3 < PAIRS) loadPair(bB, p + 3);
    }
}

// ---- split-K reduce: out = relu(bias + sum_s part[s]) ----
template <int F, int NS>
__global__ void k_reduce(const float* __restrict__ pb, const float* __restrict__ bias,
                         float* __restrict__ o, int ostride) {
    const int i = blockIdx.x * 256 + threadIdx.x;  // over N*F
    const int r = i / F, f = i % F;
    float s = bias[f];
#pragma unroll
    for (int sl = 0; sl < NS; ++sl) s += pb[(size_t)sl * N * F + i];
    o[(size_t)r * ostride + f] = fmaxf(s, 0.f);
}

// ------- kernel 5: per-block partials of Z_h = sum e^{s}, U_h = sum e^{s}(h.Wd_h)
// tanh in [-1,1] -> softmax without max-subtraction is safe.
__global__ void k_att_pool(const float* __restrict__ h, const float* __restrict__ Watt,
                           const float* __restrict__ Wd, float* __restrict__ partials) {
    __shared__ float sWa[64 * 3];
    __shared__ float sWd[192];
    for (int i = threadIdx.x; i < 192; i += blockDim.x) {
        sWa[i] = Watt[i];
        sWd[i] = Wd[i];
    }
    __syncthreads();
    const int n = blockIdx.x * blockDim.x + threadIdx.x;  // 32*256 == N exactly
    float hv[64];
#pragma unroll
    for (int q = 0; q < 16; ++q)
        *reinterpret_cast<float4*>(&hv[q * 4]) =
            *reinterpret_cast<const float4*>(&h[(size_t)n * 64 + q * 4]);
    float s0 = 0.f, s1 = 0.f, s2 = 0.f;
#pragma unroll
    for (int d = 0; d < 64; ++d) {
        s0 += hv[d] * sWa[d * 3 + 0];
        s1 += hv[d] * sWa[d * 3 + 1];
        s2 += hv[d] * sWa[d * 3 + 2];
    }
    float dot0 = 0.f, dot1 = 0.f, dot2 = 0.f;
#pragma unroll
    for (int d = 0; d < 64; ++d) {
        dot0 += hv[d] * sWd[0 * 64 + d];
        dot1 += hv[d] * sWd[1 * 64 + d];
        dot2 += hv[d] * sWd[2 * 64 + d];
    }
    const float e0 = expf(tanhf(s0));
    const float e1 = expf(tanhf(s1));
    const float e2 = expf(tanhf(s2));
    float vals[6] = {e0, e1, e2, e0 * dot0, e1 * dot1, e2 * dot2};
#pragma unroll
    for (int i = 0; i < 6; ++i) {
        float v = vals[i];
#pragma unroll
        for (int off = 1; off < 64; off <<= 1) v += __shfl_xor(v, off);
        vals[i] = v;
    }
    __shared__ float sred[4][6];
    const int wave = threadIdx.x >> 6, lane = threadIdx.x & 63;
    if (lane == 0) {
#pragma unroll
        for (int i = 0; i < 6; ++i) sred[wave][i] = vals[i];
    }
    __syncthreads();
    if (threadIdx.x == 0) {
#pragma unroll
        for (int i = 0; i < 6; ++i)
            partials[blockIdx.x * 6 + i] = sred[0][i] + sred[1][i] + sred[2][i] + sred[3][i];
    }
}

// ------------- kernel 6: out = sum_h U_h/Z_h + b_dense -------------
__global__ void k_att_final(const float* __restrict__ partials, const float* __restrict__ bd,
                            float* __restrict__ out) {
    if (threadIdx.x == 0) {
        float Z0 = 0.f, Z1 = 0.f, Z2 = 0.f, U0 = 0.f, U1 = 0.f, U2 = 0.f;
        for (int b = 0; b < 32; ++b) {
            Z0 += partials[b * 6 + 0];
            Z1 += partials[b * 6 + 1];
            Z2 += partials[b * 6 + 2];
            U0 += partials[b * 6 + 3];
            U1 += partials[b * 6 + 4];
            U2 += partials[b * 6 + 5];
        }
        out[0] = U0 / Z0 + U1 / Z1 + U2 / Z2 + bd[0];
    }
}

extern "C" void kernel_launch(void* const* d_in, const int* in_sizes, int n_in,
                              void* d_out, int out_size, void* d_ws, size_t ws_size,
                              hipStream_t stream) {
    const float* x_int   = (const float*)d_in[0];
    const float* x_nh    = (const float*)d_in[1];
    const float* adj_int = (const float*)d_in[2];
    const float* adj_nh  = (const float*)d_in[3];
    const float* W1_int  = (const float*)d_in[4];
    const float* b1_int  = (const float*)d_in[5];
    const float* W1_nh   = (const float*)d_in[6];
    const float* b1_nh   = (const float*)d_in[7];
    const float* W2_int  = (const float*)d_in[8];
    const float* b2_int  = (const float*)d_in[9];
    const float* W2_nh   = (const float*)d_in[10];
    const float* b2_nh   = (const float*)d_in[11];
    const float* W_att   = (const float*)d_in[12];
    const float* W_dense = (const float*)d_in[13];
    const float* b_dense = (const float*)d_in[14];

    float* ws = (float*)d_ws;
    float* P1T_0 = ws;                       // [16][8192]
    float* P1T_1 = ws + 131072;
    float* H1_0  = ws + 262144;              // [8192][16] row-major
    float* H1_1  = ws + 393216;
    float* P2T_0 = ws + 524288;              // [32][8192]
    float* P2T_1 = ws + 786432;
    float* hcat  = ws + 1048576;             // [8192][64] = [H2_int | H2_nh]
    float* attp  = ws + 1572864;             // [32,6]
    float* part  = ws + 1573120;             // split-K partials, reused: <=16.8MB
    float* out = (float*)d_out;

    k_dense_in<<<dim3(32, 2), 256, 0, stream>>>(x_int, x_nh, W1_int, W1_nh, P1T_0, P1T_1);
    // layer 1: F=16, W=1024, NS=8; grid.x = (8192/64)*8 = 1024; branch-serial
    k_spmm<16, 1024><<<1024, 512, 0, stream>>>(adj_int, P1T_0, part);
    k_reduce<16, 8><<<512, 256, 0, stream>>>(part, b1_int, H1_0, 16);
    k_spmm<16, 1024><<<1024, 512, 0, stream>>>(adj_nh, P1T_1, part);
    k_reduce<16, 8><<<512, 256, 0, stream>>>(part, b1_nh, H1_1, 16);
    k_dense_mid<<<dim3(32, 2), 256, 0, stream>>>(H1_0, H1_1, W2_int, W2_nh, P2T_0, P2T_1);
    // layer 2: F=32, W=512, NS=16; grid.x = (8192/64)*16 = 2048; branch-serial
    k_spmm<32, 512><<<2048, 512, 0, stream>>>(adj_int, P2T_0, part);
    k_reduce<32, 16><<<1024, 256, 0, stream>>>(part, b2_int, hcat, 64);
    k_spmm<32, 512><<<2048, 512, 0, stream>>>(adj_nh, P2T_1, part);
    k_reduce<32, 16><<<1024, 256, 0, stream>>>(part, b2_nh, hcat + 32, 64);
    k_att_pool<<<32, 256, 0, stream>>>(hcat, W_att, W_dense, attp);
    k_att_final<<<1, 64, 0, stream>>>(attp, b_dense, out);
}

// Round 9
// 613.344 us; speedup vs baseline: 3.8471x; 3.8471x over previous
//
#include <hip/hip_runtime.h>

// GNN27: two-branch diffusion GCN (N=8192, F_IN=11, F1=16, F2=32) + multi-head
// tanh-attention pooling. All fp32. Memory-bound on the two 268MB adjacencies,
// each streamed twice -> 1.07GB unique traffic.
//
// R1-R6: A as <=1KB multi-streams -> 0.9-1.9 TB/s. R7/R8: 2-8KB sequential
// runs -> raw 3.1-3.3 TB/s CONFIRMED, but R7 spilled (P-in-regs) and R8 was
// LDS-bound (reuse R=2 -> LDS:A=16:1 = 53 TB/s demand at the b128 52 TB/s
// ceiling; VALUBusy 7.6%) plus spilled in the v[64] epilogue.
// R9: engineered ratios. R=4 rows share each pv b128 read, Fw=16 cols/wave
// -> LDS:A = 4:1 (25 TB/s at full HBM rate). acc[4][16]+a[4][2] ~ 110 VGPR,
// epilogue compacts one row at a time (v[16]). W=512 (2KB runs), F=32 splits
// F across wave pairs sharing A rows. Group-0 A loads issued before staging;
// next group's loads issued under the shfl epilogue. Split-K -> k_reduce.

constexpr int N = 8192;

// ---------------- kernel 1: P1T = (x @ W1)^T   ([16][N]) ----------------
__global__ void k_dense_in(const float* __restrict__ x0, const float* __restrict__ x1,
                           const float* __restrict__ W0, const float* __restrict__ W1,
                           float* __restrict__ o0, float* __restrict__ o1) {
    const int branch = blockIdx.y;
    const float* __restrict__ x = branch ? x1 : x0;
    const float* __restrict__ W = branch ? W1 : W0;
    float* __restrict__ o = branch ? o1 : o0;
    __shared__ float sW[11 * 16];
    if (threadIdx.x < 176) sW[threadIdx.x] = W[threadIdx.x];
    __syncthreads();
    const int n = blockIdx.x * blockDim.x + threadIdx.x;  // grid.x*256 == N exactly
    float xr[11];
#pragma unroll
    for (int j = 0; j < 11; ++j) xr[j] = x[n * 11 + j];
    float acc[16];
#pragma unroll
    for (int f = 0; f < 16; ++f) acc[f] = 0.f;
#pragma unroll
    for (int j = 0; j < 11; ++j)
#pragma unroll
        for (int f = 0; f < 16; ++f) acc[f] += xr[j] * sW[j * 16 + f];
#pragma unroll
    for (int f = 0; f < 16; ++f) o[f * N + n] = acc[f];  // transposed, coalesced
}

// ---------------- kernel 3: P2T = (H1 @ W2)^T   ([32][N]) ----------------
__global__ void k_dense_mid(const float* __restrict__ h0, const float* __restrict__ h1,
                            const float* __restrict__ W0, const float* __restrict__ W1,
                            float* __restrict__ o0, float* __restrict__ o1) {
    const int branch = blockIdx.y;
    const float* __restrict__ h = branch ? h1 : h0;
    const float* __restrict__ W = branch ? W1 : W0;
    float* __restrict__ o = branch ? o1 : o0;
    __shared__ float sW[16 * 32];
    for (int i = threadIdx.x; i < 512; i += blockDim.x) sW[i] = W[i];
    __syncthreads();
    const int n = blockIdx.x * blockDim.x + threadIdx.x;
    float hr[16];
#pragma unroll
    for (int q = 0; q < 4; ++q)
        *reinterpret_cast<float4*>(&hr[q * 4]) =
            *reinterpret_cast<const float4*>(&h[n * 16 + q * 4]);
    float acc[32];
#pragma unroll
    for (int f = 0; f < 32; ++f) acc[f] = 0.f;
#pragma unroll
    for (int j = 0; j < 16; ++j)
#pragma unroll
        for (int f = 0; f < 32; ++f) acc[f] += hr[j] * sW[j * 32 + f];
#pragma unroll
    for (int f = 0; f < 32; ++f) o[f * N + n] = acc[f];  // transposed, coalesced
}

// ---- kernels 2 & 4: partial = A @ P over one K-window (W=512, split-K) ----
// Block = 512 thr = 8 waves. F=16: wave owns 8 rows (2 groups of 4), all 16 f.
// F=32: wave PAIR shares 16 rows (4 groups of 4); each wave owns 16 f.
// Per group: 8 A loads (2KB sequential per row), then per chunk c: 16 pv
// b128 reads each serving 4 rows x 4 k = 16 FMAs -> LDS:A = 4:1,
// FMA:LDS = 16:1. acc[4][16]; per-row v[16] compaction epilogue; next
// group's A loads issued under the epilogue shfls.
template <int F>
__global__ __launch_bounds__(512, 2) void k_spmm(
    const float* __restrict__ A, const float* __restrict__ PT,
    float* __restrict__ pb) {
    constexpr int W = 512;              // K-window (2KB rows)
    constexpr int NS = N / W;           // 16 K-slices
    constexpr int C = 2;                // 1KB chunks per row-window
    constexpr int FS = F / 16;          // f-slices: 1 | 2
    constexpr int G = (F == 16) ? 2 : 4;  // row-groups per wave

    __shared__ float plds[F * W];       // 32KB | 64KB

    const int tid = threadIdx.x, lane = tid & 63, w = tid >> 6;
    const int quad = w / FS;            // row-set owner
    const int f0 = (w % FS) * 16;       // f-slice base
    const int rb = blockIdx.x / NS, sl = blockIdx.x % NS;
    const int K0 = sl * W;
    const int row0 = rb * 64 + quad * 4 * G;

    const float* __restrict__ Ab = A + (size_t)row0 * N + K0 + 4 * lane;

    float4 a[4][C];
    auto loadG = [&](int g) {
#pragma unroll
        for (int r = 0; r < 4; ++r)
#pragma unroll
            for (int c = 0; c < C; ++c)  // c-inner: row's 2KB issued back-to-back
                a[r][c] = *reinterpret_cast<const float4*>(
                    Ab + (size_t)(g * 4 + r) * N + c * 256);
    };

    loadG(0);  // overlap HBM latency with staging below

    // stage P window: coalesced global read, linear LDS write (conflict-free)
    constexpr int NF4 = F * W / 4;
    for (int i = tid; i < NF4; i += 512) {
        const int fl = i / (W / 4), k4 = i % (W / 4);
        *reinterpret_cast<float4*>(&plds[fl * W + 4 * k4]) =
            *reinterpret_cast<const float4*>(PT + (size_t)fl * N + K0 + 4 * k4);
    }
    __syncthreads();

    for (int g = 0; g < G; ++g) {
        float acc[4][16];
#pragma unroll
        for (int r = 0; r < 4; ++r)
#pragma unroll
            for (int f = 0; f < 16; ++f) acc[r][f] = 0.f;

#pragma unroll
        for (int c = 0; c < C; ++c)
#pragma unroll
            for (int f = 0; f < 16; ++f) {
                const float4 pv = *reinterpret_cast<const float4*>(
                    &plds[(f0 + f) * W + c * 256 + 4 * lane]);
#pragma unroll
                for (int r = 0; r < 4; ++r) {
                    acc[r][f] += a[r][c].x * pv.x;
                    acc[r][f] += a[r][c].y * pv.y;
                    acc[r][f] += a[r][c].z * pv.z;
                    acc[r][f] += a[r][c].w * pv.w;
                }
            }

        if (g + 1 < G) loadG(g + 1);  // flies under the epilogue shfls

        // reduce each row over the 64 k-lanes: v[16] compaction (4 rounds)
        // + 16/32 xor-adds -> every lane holds red[r] for f = lane&15
        float red[4];
#pragma unroll
        for (int r = 0; r < 4; ++r) {
            float v[16];
#pragma unroll
            for (int i = 0; i < 16; ++i) v[i] = acc[r][i];
#pragma unroll
            for (int s = 0; s < 4; ++s) {
                const int bit = (lane >> s) & 1;
#pragma unroll
                for (int i = 0; i < (16 >> s); i += 2) {
                    const float t0 = __shfl_xor(v[i], 1 << s);
                    const float t1 = __shfl_xor(v[i + 1], 1 << s);
                    v[i >> 1] = bit ? (v[i + 1] + t1) : (v[i] + t0);
                }
            }
            float rs = v[0];
            rs += __shfl_xor(rs, 16);
            rs += __shfl_xor(rs, 32);
            red[r] = rs;
        }
        const int rsel = lane >> 4;
        const float val = rsel == 0 ? red[0] : rsel == 1 ? red[1] : rsel == 2 ? red[2] : red[3];
        pb[((size_t)sl * N + row0 + g * 4 + rsel) * F + f0 + (lane & 15)] = val;
    }
}

// ---- split-K reduce: out = relu(bias + sum_s part[s]) ----
template <int F, int NS>
__global__ void k_reduce(const float* __restrict__ pb, const float* __restrict__ bias,
                         float* __restrict__ o, int ostride) {
    const int i = blockIdx.x * 256 + threadIdx.x;  // over N*F
    const int r = i / F, f = i % F;
    float s = bias[f];
#pragma unroll
    for (int sl = 0; sl < NS; ++sl) s += pb[(size_t)sl * N * F + i];
    o[(size_t)r * ostride + f] = fmaxf(s, 0.f);
}

// ------- kernel 5: per-block partials of Z_h = sum e^{s}, U_h = sum e^{s}(h.Wd_h)
// tanh in [-1,1] -> softmax without max-subtraction is safe.
__global__ void k_att_pool(const float* __restrict__ h, const float* __restrict__ Watt,
                           const float* __restrict__ Wd, float* __restrict__ partials) {
    __shared__ float sWa[64 * 3];
    __shared__ float sWd[192];
    for (int i = threadIdx.x; i < 192; i += blockDim.x) {
        sWa[i] = Watt[i];
        sWd[i] = Wd[i];
    }
    __syncthreads();
    const int n = blockIdx.x * blockDim.x + threadIdx.x;  // 32*256 == N exactly
    float hv[64];
#pragma unroll
    for (int q = 0; q < 16; ++q)
        *reinterpret_cast<float4*>(&hv[q * 4]) =
            *reinterpret_cast<const float4*>(&h[(size_t)n * 64 + q * 4]);
    float s0 = 0.f, s1 = 0.f, s2 = 0.f;
#pragma unroll
    for (int d = 0; d < 64; ++d) {
        s0 += hv[d] * sWa[d * 3 + 0];
        s1 += hv[d] * sWa[d * 3 + 1];
        s2 += hv[d] * sWa[d * 3 + 2];
    }
    float dot0 = 0.f, dot1 = 0.f, dot2 = 0.f;
#pragma unroll
    for (int d = 0; d < 64; ++d) {
        dot0 += hv[d] * sWd[0 * 64 + d];
        dot1 += hv[d] * sWd[1 * 64 + d];
        dot2 += hv[d] * sWd[2 * 64 + d];
    }
    const float e0 = expf(tanhf(s0));
    const float e1 = expf(tanhf(s1));
    const float e2 = expf(tanhf(s2));
    float vals[6] = {e0, e1, e2, e0 * dot0, e1 * dot1, e2 * dot2};
#pragma unroll
    for (int i = 0; i < 6; ++i) {
        float v = vals[i];
#pragma unroll
        for (int off = 1; off < 64; off <<= 1) v += __shfl_xor(v, off);
        vals[i] = v;
    }
    __shared__ float sred[4][6];
    const int wave = threadIdx.x >> 6, lane = threadIdx.x & 63;
    if (lane == 0) {
#pragma unroll
        for (int i = 0; i < 6; ++i) sred[wave][i] = vals[i];
    }
    __syncthreads();
    if (threadIdx.x == 0) {
#pragma unroll
        for (int i = 0; i < 6; ++i)
            partials[blockIdx.x * 6 + i] = sred[0][i] + sred[1][i] + sred[2][i] + sred[3][i];
    }
}

// ------------- kernel 6: out = sum_h U_h/Z_h + b_dense -------------
__global__ void k_att_final(const float* __restrict__ partials, const float* __restrict__ bd,
                            float* __restrict__ out) {
    if (threadIdx.x == 0) {
        float Z0 = 0.f, Z1 = 0.f, Z2 = 0.f, U0 = 0.f, U1 = 0.f, U2 = 0.f;
        for (int b = 0; b < 32; ++b) {
            Z0 += partials[b * 6 + 0];
            Z1 += partials[b * 6 + 1];
            Z2 += partials[b * 6 + 2];
            U0 += partials[b * 6 + 3];
            U1 += partials[b * 6 + 4];
            U2 += partials[b * 6 + 5];
        }
        out[0] = U0 / Z0 + U1 / Z1 + U2 / Z2 + bd[0];
    }
}

extern "C" void kernel_launch(void* const* d_in, const int* in_sizes, int n_in,
                              void* d_out, int out_size, void* d_ws, size_t ws_size,
                              hipStream_t stream) {
    const float* x_int   = (const float*)d_in[0];
    const float* x_nh    = (const float*)d_in[1];
    const float* adj_int = (const float*)d_in[2];
    const float* adj_nh  = (const float*)d_in[3];
    const float* W1_int  = (const float*)d_in[4];
    const float* b1_int  = (const float*)d_in[5];
    const float* W1_nh   = (const float*)d_in[6];
    const float* b1_nh   = (const float*)d_in[7];
    const float* W2_int  = (const float*)d_in[8];
    const float* b2_int  = (const float*)d_in[9];
    const float* W2_nh   = (const float*)d_in[10];
    const float* b2_nh   = (const float*)d_in[11];
    const float* W_att   = (const float*)d_in[12];
    const float* W_dense = (const float*)d_in[13];
    const float* b_dense = (const float*)d_in[14];

    float* ws = (float*)d_ws;
    float* P1T_0 = ws;                       // [16][8192]
    float* P1T_1 = ws + 131072;
    float* H1_0  = ws + 262144;              // [8192][16] row-major
    float* H1_1  = ws + 393216;
    float* P2T_0 = ws + 524288;              // [32][8192]
    float* P2T_1 = ws + 786432;
    float* hcat  = ws + 1048576;             // [8192][64] = [H2_int | H2_nh]
    float* attp  = ws + 1572864;             // [32,6]
    float* part  = ws + 1573120;             // split-K partials, reused: <=16.8MB
    float* out = (float*)d_out;

    k_dense_in<<<dim3(32, 2), 256, 0, stream>>>(x_int, x_nh, W1_int, W1_nh, P1T_0, P1T_1);
    // layer 1: F=16, NS=16; grid = (8192/64 rows)*16 slices = 2048; branch-serial
    k_spmm<16><<<2048, 512, 0, stream>>>(adj_int, P1T_0, part);
    k_reduce<16, 16><<<512, 256, 0, stream>>>(part, b1_int, H1_0, 16);
    k_spmm<16><<<2048, 512, 0, stream>>>(adj_nh, P1T_1, part);
    k_reduce<16, 16><<<512, 256, 0, stream>>>(part, b1_nh, H1_1, 16);
    k_dense_mid<<<dim3(32, 2), 256, 0, stream>>>(H1_0, H1_1, W2_int, W2_nh, P2T_0, P2T_1);
    // layer 2: F=32, NS=16; grid = 128*16 = 2048; branch-serial
    k_spmm<32><<<2048, 512, 0, stream>>>(adj_int, P2T_0, part);
    k_reduce<32, 16><<<1024, 256, 0, stream>>>(part, b2_int, hcat, 64);
    k_spmm<32><<<2048, 512, 0, stream>>>(adj_nh, P2T_1, part);
    k_reduce<32, 16><<<1024, 256, 0, stream>>>(part, b2_nh, hcat + 32, 64);
    k_att_pool<<<32, 256, 0, stream>>>(hcat, W_att, W_dense, attp);
    k_att_final<<<1, 64, 0, stream>>>(attp, b_dense, out);
}